// Round 9
// baseline (131.487 us; speedup 1.0000x reference)
//
#include <hip/hip_runtime.h>
#include <hip/hip_bf16.h>

#define INNER 31999
#define VOCAB 32000
#define DEPTH 18
#define M_DIM 64      // B*T = 4*16
#define K_DIM 512     // D

typedef __attribute__((ext_vector_type(8))) short bf16x8;
typedef __attribute__((ext_vector_type(4))) float f32x4;
typedef __attribute__((ext_vector_type(2))) _Float16 f16x2;

// Pack two fp32 -> bf16x2 in one dword: 2x v_add_u32 (round-half-up) +
// 1x v_perm_b32. Half-up vs RTNE differs only at exact ties — absmax nil;
// NaN unreachable for finite inputs.
__device__ __forceinline__ unsigned int pkbf(float a, float b) {
    const unsigned int ua = __float_as_uint(a) + 0x8000u;
    const unsigned int ub = __float_as_uint(b) + 0x8000u;
    return __builtin_amdgcn_perm(ub, ua, 0x07060302u);  // [a.hi16 | b.hi16]
}

__device__ __forceinline__ bf16x8 cvt8(f32x4 lo, f32x4 hi) {
    union { unsigned int u[4]; bf16x8 v; } r;
    r.u[0] = pkbf(lo[0], lo[1]);
    r.u[1] = pkbf(lo[2], lo[3]);
    r.u[2] = pkbf(hi[0], hi[1]);
    r.u[3] = pkbf(hi[2], hi[3]);
    return r.v;
}

// Kernel 0: one-shot att fp32 -> bf16, pre-swizzled into MFMA B-fragment
// order: attbG[k0i][j][lane][8] where lane=quad*16+mrow reads
// att[m=j*16+mrow][k=k0i*32+quad*8 .. +7].  64 KB total.  Makes every GEMM
// block's staging a pure coalesced 64 KB copy (no pack VALU, half the bytes).
__global__ __launch_bounds__(256) void swz_att_kernel(
    const float* __restrict__ att, unsigned short* __restrict__ attbG)
{
    const int t = blockIdx.x * 256 + threadIdx.x;   // 0..4095, one 16B frag each
    const int lane = t & 63;
    const int j    = (t >> 6) & 3;
    const int k0i  = t >> 8;
    const int mrow = lane & 15;
    const int quad = lane >> 4;
    const f32x4* p = (const f32x4*)(att + (j * 16 + mrow) * K_DIM + k0i * 32 + quad * 8);
    const f32x4 lo = p[0], hi = p[1];
    uint4 o;
    o.x = pkbf(lo[0], lo[1]);
    o.y = pkbf(lo[2], lo[3]);
    o.z = pkbf(hi[0], hi[1]);
    o.w = pkbf(hi[2], hi[3]);
    ((uint4*)attbG)[t] = o;
}

// Kernel 1: xT[n][m] = sum_k W[n][k]*att[m][k], bf16 MFMA, fp32 accum, fp16 out.
// R7 structure (known-good: grid 500, 2 blocks/CU, 8 waves/CU — R8 showed
// wave supply is the binding constraint, NOT the prologue).  R9 change:
// staging is now a bare 64 KB fragment-ordered copy from attbG; in-loop
// ds_read_b128 at wave-uniform + lane*16 (even 8 dwords/bank, conflict-free).
__global__ __launch_bounds__(256) void gemm_xt_kernel(
    const float* __restrict__ W,              // [31999][512] fp32
    const unsigned short* __restrict__ attbG, // fragment-ordered bf16, 64 KB
    _Float16* __restrict__ xT)                // [32000][64] fp16
{
    __shared__ __align__(16) unsigned short attb[M_DIM * K_DIM];  // 64 KB

    const int tid  = threadIdx.x;
    const int wave = tid >> 6;
    const int lane = tid & 63;
    const int mrow = lane & 15;
    const int quad = lane >> 4;

    // Stage: 16 iters x 256 thr x 16 B = 64 KB, fully coalesced, zero VALU.
    #pragma unroll
    for (int i = 0; i < 16; i++) {
        const int e = i * 256 + tid;
        ((uint4*)attb)[e] = ((const uint4*)attbG)[e];
    }
    __syncthreads();

    // Clamp the single OOB row (n==31999); its xT row is never gathered.
    const int n_base = blockIdx.x * 64 + wave * 16;
    const int n = n_base + mrow;
    const int nc = n < INNER ? n : (INNER - 1);
    const float* wp = W + (size_t)nc * K_DIM;

    f32x4 acc[4];
    #pragma unroll
    for (int j = 0; j < 4; j++) acc[j] = (f32x4){0.f, 0.f, 0.f, 0.f};

    #pragma unroll
    for (int k0i = 0; k0i < 16; k0i++) {
        const int koff = k0i * 32 + quad * 8;    // this lane's 8 k values
        const f32x4* p = (const f32x4*)(wp + koff);
        const bf16x8 a = cvt8(p[0], p[1]);       // W rows: A operand (perm-pack)
        #pragma unroll
        for (int j = 0; j < 4; j++) {
            const bf16x8 b = *(const bf16x8*)(attb + ((k0i * 4 + j) * 64 + lane) * 8);
            acc[j] = __builtin_amdgcn_mfma_f32_16x16x32_bf16(a, b, acc[j], 0, 0, 0);
        }
    }

    // D layout: col(lane&15) = m-within-16, row(quad*4+reg) = W-row offset.
    #pragma unroll
    for (int j = 0; j < 4; j++) {
        const int m = j * 16 + mrow;
        #pragma unroll
        for (int r = 0; r < 4; r++)
            xT[(size_t)(n_base + quad * 4 + r) * M_DIM + m] = (_Float16)acc[j][r];
    }
}

// Kernel 2: out[m][v] = sum_d clamp(logsigmoid(s*x), log eps, 0)
//   = sum_d min(y_d,0) - log( prod_d (1 + exp(-|y_d|)) )   [one log per output]
// prod in (1, 2^18]: <=18 ulp rel err. Per-d clip never fires (|x| <~ 6).
// Each half-wave covers one v: lane handles m = 2*sub, 2*sub+1 via a single
// dword gather (256 B/wave-inst coalesced row reads of fp16 xT).
__global__ __launch_bounds__(256) void hsoftmax_kernel(
    const _Float16* __restrict__ xT,       // [32000][64] fp16
    const int*   __restrict__ path_index,  // [VOCAB*DEPTH]
    const float* __restrict__ path_sign,   // [VOCAB*DEPTH]
    float* __restrict__ out)               // [64][32000]
{
    __shared__ unsigned int packed[32 * DEPTH];   // idx | signbit (idx < 2^15)
    __shared__ float2 res2[32][33];               // [v][m/2], 264B rows

    const int tid = threadIdx.x;
    const int wave = tid >> 6;
    const int lane = tid & 63;
    const int half = lane >> 5;                   // which v of the pair
    const int sub  = lane & 31;                   // m = 2*sub, 2*sub+1
    const int v_base = blockIdx.x * 32;
    const int base = v_base * DEPTH;

    for (int t = tid; t < 32 * DEPTH; t += 256) {
        const unsigned int idx = (unsigned int)path_index[base + t];
        const float s = path_sign[base + t];
        packed[t] = idx | (s < 0.f ? 0x80000000u : 0u);
    }
    __syncthreads();

    for (int i = 0; i < 4; i++) {
        const int vloc = wave * 8 + 2 * i + half;
        float accmin0 = 0.f, accmin1 = 0.f;
        float prod0 = 1.f, prod1 = 1.f;
        #pragma unroll
        for (int d = 0; d < DEPTH; d++) {
            const unsigned int p = packed[vloc * DEPTH + d];   // 2-way broadcast
            const unsigned int xx = *(const unsigned int*)(
                (const unsigned short*)xT + (p & 0x7fffu) * M_DIM + sub * 2);
            union { unsigned int u; f16x2 h; } cv; cv.u = xx;
            const float x0 = (float)cv.h[0];
            const float x1 = (float)cv.h[1];
            const unsigned int sgn = p & 0x80000000u;
            const unsigned int xb0 = __float_as_uint(x0);
            const unsigned int xb1 = __float_as_uint(x1);
            const float e0 = __expf(__uint_as_float(xb0 | 0x80000000u)); // e^{-|y|}
            const float e1 = __expf(__uint_as_float(xb1 | 0x80000000u));
            prod0 = fmaf(prod0, e0, prod0);        // prod *= (1 + e)
            prod1 = fmaf(prod1, e1, prod1);
            accmin0 += fminf(__uint_as_float(xb0 ^ sgn), 0.f);  // min(s*x, 0)
            accmin1 += fminf(__uint_as_float(xb1 ^ sgn), 0.f);
        }
        const float r0 = fmaxf(accmin0 - __logf(prod0), -373.1f); // 18*log(1e-9)
        const float r1 = fmaxf(accmin1 - __logf(prod1), -373.1f);
        res2[vloc][sub] = make_float2(r0, r1);
    }
    __syncthreads();

    // Coalesced stores: 256 thr x 8 iters cover 64 m x 32 v.
    #pragma unroll
    for (int it = 0; it < 8; it++) {
        const int m = it * 8 + (tid >> 5);
        const int vloc = tid & 31;
        out[(size_t)m * VOCAB + v_base + vloc] = ((const float*)&res2[vloc][0])[m];
    }
}

extern "C" void kernel_launch(void* const* d_in, const int* in_sizes, int n_in,
                              void* d_out, int out_size, void* d_ws, size_t ws_size,
                              hipStream_t stream) {
    const float* att        = (const float*)d_in[0];
    const float* W          = (const float*)d_in[1];
    const int*   path_index = (const int*)d_in[2];
    const float* path_sign  = (const float*)d_in[3];
    // d_in[4] = path_bias: algebraically redundant ((1-sign)/2), unused.

    _Float16* xT = (_Float16*)d_ws;        // 32000*64*2 = 4.096 MB scratch
    unsigned short* attbG = (unsigned short*)((char*)d_ws + (size_t)VOCAB * M_DIM * 2); // 64 KB
    float* out = (float*)d_out;

    swz_att_kernel<<<16, 256, 0, stream>>>(att, attbG);
    gemm_xt_kernel<<<500, 256, 0, stream>>>(W, attbG, xT);
    hsoftmax_kernel<<<1000, 256, 0, stream>>>(xT, path_index, path_sign, out);
}

// Round 10
// 122.329 us; speedup vs baseline: 1.0749x; 1.0749x over previous
//
#include <hip/hip_runtime.h>
#include <hip/hip_bf16.h>

#define INNER 31999
#define VOCAB 32000
#define DEPTH 18
#define M_DIM 64      // B*T = 4*16
#define K_DIM 512     // D
#define LDS_K (K_DIM + 8)   // +8 bf16 pad -> 2-way-max (free) ds_read_b128

typedef __attribute__((ext_vector_type(8))) short bf16x8;
typedef __attribute__((ext_vector_type(4))) short s16x4;
typedef __attribute__((ext_vector_type(4))) float f32x4;
typedef __attribute__((ext_vector_type(2))) _Float16 f16x2;

// Pack two fp32 -> bf16x2 in one dword: 2x v_add_u32 (round-half-up) +
// 1x v_perm_b32 (take hi16 of each). Half-up vs RTNE differs only at exact
// ties — absmax impact nil; NaN unreachable for finite inputs.
__device__ __forceinline__ unsigned int pkbf(float a, float b) {
    const unsigned int ua = __float_as_uint(a) + 0x8000u;
    const unsigned int ub = __float_as_uint(b) + 0x8000u;
    return __builtin_amdgcn_perm(ub, ua, 0x07060302u);  // [a.hi16 | b.hi16]
}

__device__ __forceinline__ bf16x8 cvt8(f32x4 lo, f32x4 hi) {
    union { unsigned int u[4]; bf16x8 v; } r;
    r.u[0] = pkbf(lo[0], lo[1]);
    r.u[1] = pkbf(lo[2], lo[3]);
    r.u[2] = pkbf(hi[0], hi[1]);
    r.u[3] = pkbf(hi[2], hi[3]);
    return r.v;
}

// Kernel 1: xT[n][m] = sum_k W[n][k]*att[m][k], bf16 MFMA, fp32 accum, fp16 out.
// KNOWN-BEST (R7, 121.0 us): att staged+packed to LDS once per block, full-K
// unroll, grid 500 = 2 blocks/CU = 8 waves/CU. Measured lessons:
//  - R8 (grid 250, 2 tiles/block): +8 us — wave supply, not prologue, binds.
//  - R9 (pre-swizzled att + 3rd launch): +10 us — extra launch + unoverlapped
//    staging copy cost more than the pack VALU it removed.
__global__ __launch_bounds__(256) void gemm_xt_kernel(
    const float* __restrict__ W,     // [31999][512] fp32
    const float* __restrict__ att,   // [64][512] fp32
    _Float16* __restrict__ xT)       // [32000][64] fp16
{
    __shared__ __align__(16) unsigned short attb[M_DIM * LDS_K];  // 65 KB bf16

    const int tid  = threadIdx.x;
    const int wave = tid >> 6;
    const int lane = tid & 63;
    const int mrow = lane & 15;
    const int quad = lane >> 4;

    // Stage att (128 KB fp32, L2/L3-resident) -> LDS bf16, coalesced, once.
    #pragma unroll
    for (int i = 0; i < 32; i++) {
        const int f4 = i * 256 + tid;            // float4 index, 0..8191
        const f32x4 v = ((const f32x4*)att)[f4];
        const int f = f4 * 4;
        const int m = f >> 9, k = f & (K_DIM - 1);
        union { unsigned int u[2]; s16x4 s; } o;
        o.u[0] = pkbf(v[0], v[1]);
        o.u[1] = pkbf(v[2], v[3]);
        *(s16x4*)(attb + m * LDS_K + k) = o.s;   // 8 B, aligned (k % 4 == 0)
    }
    __syncthreads();

    // Clamp the single OOB row (n==31999); its xT row is never gathered.
    const int n_base = blockIdx.x * 64 + wave * 16;
    const int n = n_base + mrow;
    const int nc = n < INNER ? n : (INNER - 1);
    const float* wp = W + (size_t)nc * K_DIM;

    f32x4 acc[4];
    #pragma unroll
    for (int j = 0; j < 4; j++) acc[j] = (f32x4){0.f, 0.f, 0.f, 0.f};

    #pragma unroll
    for (int k0i = 0; k0i < 16; k0i++) {
        const int koff = k0i * 32 + quad * 8;    // this lane's 8 k values
        const f32x4* p = (const f32x4*)(wp + koff);
        const bf16x8 a = cvt8(p[0], p[1]);       // W rows: A operand (perm-pack)
        #pragma unroll
        for (int j = 0; j < 4; j++) {
            const bf16x8 b = *(const bf16x8*)(attb + (j * 16 + mrow) * LDS_K + koff);
            acc[j] = __builtin_amdgcn_mfma_f32_16x16x32_bf16(a, b, acc[j], 0, 0, 0);
        }
    }

    // D layout: col(lane&15) = m-within-16, row(quad*4+reg) = W-row offset.
    #pragma unroll
    for (int j = 0; j < 4; j++) {
        const int m = j * 16 + mrow;
        #pragma unroll
        for (int r = 0; r < 4; r++)
            xT[(size_t)(n_base + quad * 4 + r) * M_DIM + m] = (_Float16)acc[j][r];
    }
}

// Kernel 2: out[m][v] = sum_d clamp(logsigmoid(s*x), log eps, 0)
//   = sum_d min(y_d,0) - log( prod_d (1 + exp(-|y_d|)) )   [one log per output]
// prod in (1, 2^18]: <=18 ulp rel err. Per-d clip never fires (|x| <~ 6).
// Each half-wave covers one v: lane handles m = 2*sub, 2*sub+1 via a single
// dword gather (256 B/wave-inst coalesced row reads of fp16 xT).
__global__ __launch_bounds__(256) void hsoftmax_kernel(
    const _Float16* __restrict__ xT,       // [32000][64] fp16
    const int*   __restrict__ path_index,  // [VOCAB*DEPTH]
    const float* __restrict__ path_sign,   // [VOCAB*DEPTH]
    float* __restrict__ out)               // [64][32000]
{
    __shared__ unsigned int packed[32 * DEPTH];   // idx | signbit (idx < 2^15)
    __shared__ float2 res2[32][33];               // [v][m/2], 264B rows

    const int tid = threadIdx.x;
    const int wave = tid >> 6;
    const int lane = tid & 63;
    const int half = lane >> 5;                   // which v of the pair
    const int sub  = lane & 31;                   // m = 2*sub, 2*sub+1
    const int v_base = blockIdx.x * 32;
    const int base = v_base * DEPTH;

    for (int t = tid; t < 32 * DEPTH; t += 256) {
        const unsigned int idx = (unsigned int)path_index[base + t];
        const float s = path_sign[base + t];
        packed[t] = idx | (s < 0.f ? 0x80000000u : 0u);
    }
    __syncthreads();

    for (int i = 0; i < 4; i++) {
        const int vloc = wave * 8 + 2 * i + half;
        float accmin0 = 0.f, accmin1 = 0.f;
        float prod0 = 1.f, prod1 = 1.f;
        #pragma unroll
        for (int d = 0; d < DEPTH; d++) {
            const unsigned int p = packed[vloc * DEPTH + d];   // 2-way broadcast
            const unsigned int xx = *(const unsigned int*)(
                (const unsigned short*)xT + (p & 0x7fffu) * M_DIM + sub * 2);
            union { unsigned int u; f16x2 h; } cv; cv.u = xx;
            const float x0 = (float)cv.h[0];
            const float x1 = (float)cv.h[1];
            const unsigned int sgn = p & 0x80000000u;
            const unsigned int xb0 = __float_as_uint(x0);
            const unsigned int xb1 = __float_as_uint(x1);
            const float e0 = __expf(__uint_as_float(xb0 | 0x80000000u)); // e^{-|y|}
            const float e1 = __expf(__uint_as_float(xb1 | 0x80000000u));
            prod0 = fmaf(prod0, e0, prod0);        // prod *= (1 + e)
            prod1 = fmaf(prod1, e1, prod1);
            accmin0 += fminf(__uint_as_float(xb0 ^ sgn), 0.f);  // min(s*x, 0)
            accmin1 += fminf(__uint_as_float(xb1 ^ sgn), 0.f);
        }
        const float r0 = fmaxf(accmin0 - __logf(prod0), -373.1f); // 18*log(1e-9)
        const float r1 = fmaxf(accmin1 - __logf(prod1), -373.1f);
        res2[vloc][sub] = make_float2(r0, r1);
    }
    __syncthreads();

    // Coalesced stores: 256 thr x 8 iters cover 64 m x 32 v.
    #pragma unroll
    for (int it = 0; it < 8; it++) {
        const int m = it * 8 + (tid >> 5);
        const int vloc = tid & 31;
        out[(size_t)m * VOCAB + v_base + vloc] = ((const float*)&res2[vloc][0])[m];
    }
}

extern "C" void kernel_launch(void* const* d_in, const int* in_sizes, int n_in,
                              void* d_out, int out_size, void* d_ws, size_t ws_size,
                              hipStream_t stream) {
    const float* att        = (const float*)d_in[0];
    const float* W          = (const float*)d_in[1];
    const int*   path_index = (const int*)d_in[2];
    const float* path_sign  = (const float*)d_in[3];
    // d_in[4] = path_bias: algebraically redundant ((1-sign)/2), unused.

    _Float16* xT = (_Float16*)d_ws;        // 32000*64*2 = 4.096 MB scratch
    float* out = (float*)d_out;

    gemm_xt_kernel<<<500, 256, 0, stream>>>(W, att, xT);
    hsoftmax_kernel<<<1000, 256, 0, stream>>>(xT, path_index, path_sign, out);
}